// Round 1
// baseline (507.136 us; speedup 1.0000x reference)
//
#include <hip/hip_runtime.h>

// x: (B, N+1, D) fp32, significance: (B, N) fp32, keep_tokens K=1024
constexpr int B    = 32;
constexpr int NTOK = 4096;
constexpr int D    = 768;
constexpr int K    = 1024;
constexpr int D4   = D / 4;      // 192 float4 per row
constexpr int ROWS = 5;          // rows per gather block; 1025 = 5 * 205
constexpr int GPB  = 205;        // gather groups per batch

// clang vector type (usable with nontemporal builtins, unlike HIP float4)
typedef float vfloat4 __attribute__((ext_vector_type(4)));

// Map float bits to unsigned so unsigned compare == float compare.
__device__ __forceinline__ unsigned monotone_u32(float f) {
  unsigned u = __float_as_uint(f);
  return (u & 0x80000000u) ? ~u : (u | 0x80000000u);
}

// key = (~monotone(v) << 32) | token_idx
// ascending key order == descending value, ties -> smaller index (jax semantics).
__device__ __forceinline__ unsigned long long mkkey(float v, unsigned gidx) {
  return ((unsigned long long)(~monotone_u32(v)) << 32) | gidx;
}

// Fused per-batch top-K: full 4096-key bitonic sort in LDS, with the final
// k=4096 merge truncated to the lowest-1024 prefix (only top-K needed).
// 32 blocks x 1024 threads, 32 KB LDS.
__global__ __launch_bounds__(1024)
void topk_sort(const float* __restrict__ sig, int* __restrict__ idx) {
  __shared__ unsigned long long keys[NTOK];
  const int b = blockIdx.x;
  const float* s = sig + (size_t)b * NTOK;

  #pragma unroll
  for (int rep = 0; rep < 4; ++rep) {
    int i = threadIdx.x + rep * 1024;
    keys[i] = mkkey(s[i], i);
  }
  __syncthreads();

  // Full bitonic stages k = 2 .. 2048 (identical to monolithic sort).
  for (int k = 2; k <= 2048; k <<= 1) {
    for (int j = k >> 1; j > 0; j >>= 1) {
      #pragma unroll
      for (int rep = 0; rep < 2; ++rep) {
        int p = threadIdx.x + rep * 1024;           // 2048 pairs
        int i = ((p & ~(j - 1)) << 1) | (p & (j - 1));
        bool dir = ((i & k) == 0);
        unsigned long long a = keys[i], d = keys[i | j];
        if ((a > d) == dir) { keys[i] = d; keys[i | j] = a; }
      }
      __syncthreads();
    }
  }

  // Final stage (k = 4096, ascending), truncated to the first K outputs.
  // j = 2048: all pairs (i, i+2048), i in [0,2048)
  #pragma unroll
  for (int rep = 0; rep < 2; ++rep) {
    int i = threadIdx.x + rep * 1024;
    unsigned long long a = keys[i], d = keys[i + 2048];
    if (a > d) { keys[i] = d; keys[i + 2048] = a; }
  }
  __syncthreads();
  // j = 1024: only pairs settling the lower half, i in [0,1024)
  {
    int i = threadIdx.x;
    unsigned long long a = keys[i], d = keys[i + 1024];
    if (a > d) { keys[i] = d; keys[i + 1024] = a; }
  }
  __syncthreads();
  // j = 512..1: bitonic merge of [0,1024) — the 1024 smallest keys.
  for (int j = 512; j > 0; j >>= 1) {
    if (threadIdx.x < 512) {
      int p = threadIdx.x;
      int i = ((p & ~(j - 1)) << 1) | (p & (j - 1));
      unsigned long long a = keys[i], d = keys[i | j];
      if (a > d) { keys[i] = d; keys[i | j] = a; }
    }
    __syncthreads();
  }

  idx[b * K + threadIdx.x] = (int)(unsigned)(keys[threadIdx.x] & 0xffffffffu);
}

// Gather: one block per 5 output rows (never crosses a batch: 1025 = 5*205).
// 192 threads x float4 per row; x/out are pure streaming -> nontemporal.
__global__ __launch_bounds__(D4)
void gather_kernel(const vfloat4* __restrict__ x, const int* __restrict__ idx,
                   vfloat4* __restrict__ out) {
  const int blk = blockIdx.x;
  const int b   = blk / GPB;
  const int g   = blk - b * GPB;
  const int r0  = g * ROWS;

  int src_row[ROWS];
  #pragma unroll
  for (int q = 0; q < ROWS; ++q) {
    int r = r0 + q;
    src_row[q] = (r == 0) ? 0 : 1 + idx[b * K + r - 1];
  }

  #pragma unroll
  for (int q = 0; q < ROWS; ++q) {
    int r = r0 + q;
    const size_t src = ((size_t)b * (NTOK + 1) + src_row[q]) * D4 + threadIdx.x;
    const size_t dst = ((size_t)b * (K + 1) + r) * D4 + threadIdx.x;
    vfloat4 v = __builtin_nontemporal_load(&x[src]);
    __builtin_nontemporal_store(v, &out[dst]);
  }
}

extern "C" void kernel_launch(void* const* d_in, const int* in_sizes, int n_in,
                              void* d_out, int out_size, void* d_ws, size_t ws_size,
                              hipStream_t stream) {
  const float* x   = (const float*)d_in[0];
  const float* sig = (const float*)d_in[1];
  float* out = (float*)d_out;

  int* idx = (int*)d_ws;   // 32*1024*4 = 128 KB of workspace

  topk_sort   <<<B,       1024, 0, stream>>>(sig, idx);
  gather_kernel<<<B * GPB, D4,  0, stream>>>((const vfloat4*)x, idx, (vfloat4*)out);
}